// Round 3
// baseline (317.118 us; speedup 1.0000x reference)
//
#include <hip/hip_runtime.h>
#include <hip/hip_bf16.h>
#include <math.h>

// Problem constants (from reference)
#define NN 20000      // nodes
#define NE 320000     // edges
#define FT 8          // tokens per node
#define DM 16         // embed dim
#define NH 4          // heads
#define DH 4          // head dim
#define FD 128        // FT*DM
#define OUTC 7        // classes
#define NFD (NN * FD)

typedef unsigned short ushort;

__device__ inline float bf2f(ushort u) {
    union { unsigned int i; float f; } c; c.i = ((unsigned int)u) << 16; return c.f;
}
__device__ inline ushort f2bf(float f) {
    union { float f; unsigned int u; } c; c.f = f;
    unsigned int r = c.u + 0x7FFFu + ((c.u >> 16) & 1u);  // RNE
    return (ushort)(r >> 16);
}

// ---------------------------------------------------------------------------
// Per-node QKV projection. q kept fp32 [n][128]; K and V packed bf16 into one
// interleaved row kv[n][256]: [0..127]=K (f*16+d), [128..255]=V. Row = 512B.
// One block (128 threads) per node; thread t -> (f = t>>4, d = t&15).
// ---------------------------------------------------------------------------
__global__ __launch_bounds__(128) void qkv_kernel(
    const float* __restrict__ x,
    const float* __restrict__ wqkv,   // [48][16]
    const float* __restrict__ bqkv,   // [48]
    float* __restrict__ q, ushort* __restrict__ kv) {
    __shared__ float sx[FD];
    __shared__ float sw[48 * 17];
    __shared__ float sb[48];
    __shared__ ushort skv[256];
    const int n = blockIdx.x;
    const int t = threadIdx.x;
    sx[t] = x[n * FD + t];
    for (int i = t; i < 48 * DM; i += 128) sw[(i >> 4) * 17 + (i & 15)] = wqkv[i];
    if (t < 48) sb[t] = bqkv[t];
    __syncthreads();
    const int f = t >> 4, d = t & 15;
    float aq = sb[d], ak = sb[DM + d], av = sb[2 * DM + d];
    const float* xr = &sx[f * DM];
#pragma unroll
    for (int e = 0; e < DM; ++e) {
        const float xe = xr[e];
        aq = fmaf(xe, sw[d * 17 + e], aq);
        ak = fmaf(xe, sw[(DM + d) * 17 + e], ak);
        av = fmaf(xe, sw[(2 * DM + d) * 17 + e], av);
    }
    q[n * FD + t] = aq;
    skv[t] = f2bf(ak);
    skv[128 + t] = f2bf(av);
    __syncthreads();
    if (t < 32) ((uint4*)(kv + n * 256))[t] = ((const uint4*)skv)[t];
}

// ---------------------------------------------------------------------------
// deg[n] = in-degree at dst
// ---------------------------------------------------------------------------
__global__ __launch_bounds__(256) void deg_kernel(const int* __restrict__ dst,
                                                  int* __restrict__ deg) {
    const int e = blockIdx.x * 256 + threadIdx.x;
    if (e < NE) atomicAdd(&deg[dst[e]], 1);
}

// ---------------------------------------------------------------------------
// Single-block exclusive prefix scan of deg[0..NN) -> rowstart, cursor.
// ---------------------------------------------------------------------------
__global__ __launch_bounds__(1024) void scan_kernel(const int* __restrict__ deg,
                                                    int* __restrict__ rowstart,
                                                    int* __restrict__ cursor) {
    __shared__ int wsum[16];
    __shared__ int s_carry;
    const int t = threadIdx.x;
    const int lane = t & 63, wid = t >> 6;
    if (t == 0) s_carry = 0;
    __syncthreads();
    for (int base = 0; base < NN; base += 1024) {
        const int i = base + t;
        const int d = (i < NN) ? deg[i] : 0;
        int s = d;
        for (int off = 1; off < 64; off <<= 1) {
            int tmp = __shfl_up(s, off);
            if (lane >= off) s += tmp;
        }
        if (lane == 63) wsum[wid] = s;
        __syncthreads();
        if (wid == 0) {
            int ws = (lane < 16) ? wsum[lane] : 0;
            for (int off = 1; off < 16; off <<= 1) {
                int tmp = __shfl_up(ws, off);
                if (lane >= off) ws += tmp;
            }
            if (lane < 16) wsum[lane] = ws;
        }
        __syncthreads();
        const int carry = s_carry;
        const int woff = (wid > 0) ? wsum[wid - 1] : 0;
        if (i < NN) {
            const int excl = carry + woff + s - d;
            rowstart[i] = excl;
            cursor[i] = excl;
        }
        __syncthreads();
        if (t == 1023) s_carry = carry + wsum[15];
        __syncthreads();
    }
    if (t == 0) rowstart[NN] = NE;
}

// ---------------------------------------------------------------------------
// Scatter edges into CSR order
// ---------------------------------------------------------------------------
__global__ __launch_bounds__(256) void scatter_kernel(
    const int* __restrict__ src, const int* __restrict__ dst,
    int* __restrict__ cursor, int* __restrict__ csr_src) {
    const int e = blockIdx.x * 256 + threadIdx.x;
    if (e < NE) {
        const int pos = atomicAdd(&cursor[dst[e]], 1);
        csr_src[pos] = src[e];
    }
}

// ---------------------------------------------------------------------------
// Per-node edge aggregation. One 64-lane wave per dst node; 32-lane half per
// edge stream; 2-edge unroll per half (4 edges in flight per wave) + 1-deep
// CSR index prefetch. K/V gathered as bf16 (512B/edge vs 1KB fp32), math fp32.
// Masked tail edges contribute via inv=0 (no divergence around compute).
// ---------------------------------------------------------------------------
__global__ __launch_bounds__(256) void edge_agg_kernel(
    const int* __restrict__ rowstart, const int* __restrict__ csr_src,
    const float* __restrict__ q, const ushort* __restrict__ kv,
    float* __restrict__ accum) {
    const int w = (blockIdx.x * 256 + threadIdx.x) >> 6;  // wave id = node
    if (w >= NN) return;
    const int lane = threadIdx.x & 63;
    const int hl = lane & 31;
    const int half = lane >> 5;
    const int h = hl & 3;

    const float4 qv = *(const float4*)(q + w * FD + hl * 4);
    const int beg = rowstart[w];
    const int end = rowstart[w + 1];

    float o0 = 0.f, o1 = 0.f, o2 = 0.f, o3 = 0.f;

    int e = beg + half;
    int sA = (e < end) ? csr_src[e] : 0;
    int sB = (e + 2 < end) ? csr_src[e + 2] : 0;
    for (; e < end; e += 4) {
        const int cA = sA, cB = sB;
        const float mB = (e + 2 < end) ? 1.0f : 0.0f;
        sA = (e + 4 < end) ? csr_src[e + 4] : 0;
        sB = (e + 6 < end) ? csr_src[e + 6] : 0;

        const ushort* ra = kv + cA * 256;
        const ushort* rb = kv + cB * 256;
        ushort4 kA[FT], vA[FT], kB[FT], vB[FT];
#pragma unroll
        for (int g = 0; g < FT; ++g) {
            kA[g] = *(const ushort4*)(ra + g * 16 + h * 4);
            vA[g] = *(const ushort4*)(ra + 128 + g * 16 + h * 4);
            kB[g] = *(const ushort4*)(rb + g * 16 + h * 4);
            vB[g] = *(const ushort4*)(rb + 128 + g * 16 + h * 4);
        }
        float sa[FT], sb[FT];
#pragma unroll
        for (int g = 0; g < FT; ++g) {
            sa[g] = 0.5f * (qv.x * bf2f(kA[g].x) + qv.y * bf2f(kA[g].y) +
                            qv.z * bf2f(kA[g].z) + qv.w * bf2f(kA[g].w));
            sb[g] = 0.5f * (qv.x * bf2f(kB[g].x) + qv.y * bf2f(kB[g].y) +
                            qv.z * bf2f(kB[g].z) + qv.w * bf2f(kB[g].w));
        }
        float ma = sa[0], mb = sb[0];
#pragma unroll
        for (int g = 1; g < FT; ++g) { ma = fmaxf(ma, sa[g]); mb = fmaxf(mb, sb[g]); }
        float suma = 0.f, sumb = 0.f;
#pragma unroll
        for (int g = 0; g < FT; ++g) {
            sa[g] = __expf(sa[g] - ma); suma += sa[g];
            sb[g] = __expf(sb[g] - mb); sumb += sb[g];
        }
        const float invA = 1.0f / suma;
        const float invB = mB / sumb;
#pragma unroll
        for (int g = 0; g < FT; ++g) {
            const float pA = sa[g] * invA;
            const float pB = sb[g] * invB;
            o0 = fmaf(pA, bf2f(vA[g].x), fmaf(pB, bf2f(vB[g].x), o0));
            o1 = fmaf(pA, bf2f(vA[g].y), fmaf(pB, bf2f(vB[g].y), o1));
            o2 = fmaf(pA, bf2f(vA[g].z), fmaf(pB, bf2f(vB[g].z), o2));
            o3 = fmaf(pA, bf2f(vA[g].w), fmaf(pB, bf2f(vB[g].w), o3));
        }
    }
    o0 += __shfl_xor(o0, 32);
    o1 += __shfl_xor(o1, 32);
    o2 += __shfl_xor(o2, 32);
    o3 += __shfl_xor(o3, 32);
    if (half == 0)
        *(float4*)(accum + w * FD + hl * 4) = make_float4(o0, o1, o2, o3);
}

// ---------------------------------------------------------------------------
// Per-node epilogue: h = ELU(accum @ Wo^T + deg * bo)
// ---------------------------------------------------------------------------
__global__ __launch_bounds__(128) void node_post_kernel(
    const float* __restrict__ accum, const int* __restrict__ deg,
    const float* __restrict__ wo,   // [16][16]
    const float* __restrict__ bo,   // [16]
    float* __restrict__ h) {
    __shared__ float sa[FD];
    __shared__ float sw[DM * 17];
    __shared__ float sb[DM];
    const int n = blockIdx.x;
    const int t = threadIdx.x;
    sa[t] = accum[n * FD + t];
    for (int i = t; i < DM * DM; i += 128) sw[(i >> 4) * 17 + (i & 15)] = wo[i];
    if (t < DM) sb[t] = bo[t];
    __syncthreads();
    const int f = t >> 4, d = t & 15;
    float acc = (float)deg[n] * sb[d];
#pragma unroll
    for (int e = 0; e < DM; ++e) acc = fmaf(sa[f * DM + e], sw[d * 17 + e], acc);
    h[n * FD + t] = acc > 0.f ? acc : expm1f(acc);
}

// ---------------------------------------------------------------------------
// Classifier: logits = h @ W^T + b; log_softmax. One wave per node.
// ---------------------------------------------------------------------------
__global__ __launch_bounds__(256) void classifier_kernel(
    const float* __restrict__ h, const float* __restrict__ w,  // [7][128]
    const float* __restrict__ b, float* __restrict__ out) {
    const int lane = threadIdx.x & 63;
    const int n = blockIdx.x * 4 + (threadIdx.x >> 6);
    if (n >= NN) return;
    const float h0 = h[n * FD + lane];
    const float h1 = h[n * FD + 64 + lane];
    float acc[OUTC];
#pragma unroll
    for (int c = 0; c < OUTC; ++c)
        acc[c] = h0 * w[c * FD + lane] + h1 * w[c * FD + 64 + lane];
#pragma unroll
    for (int c = 0; c < OUTC; ++c) {
        float a = acc[c];
        for (int off = 32; off; off >>= 1) a += __shfl_xor(a, off);
        acc[c] = a;
    }
    if (lane == 0) {
        float logits[OUTC];
        float m = -1e30f;
#pragma unroll
        for (int c = 0; c < OUTC; ++c) { logits[c] = acc[c] + b[c]; m = fmaxf(m, logits[c]); }
        float s = 0.f;
#pragma unroll
        for (int c = 0; c < OUTC; ++c) s += __expf(logits[c] - m);
        const float lse = m + logf(s);
#pragma unroll
        for (int c = 0; c < OUTC; ++c) out[n * OUTC + c] = logits[c] - lse;
    }
}

extern "C" void kernel_launch(void* const* d_in, const int* in_sizes, int n_in,
                              void* d_out, int out_size, void* d_ws, size_t ws_size,
                              hipStream_t stream) {
    const float* x      = (const float*)d_in[0];
    const int*   ei     = (const int*)d_in[1];
    const float* w1qkv  = (const float*)d_in[2];
    const float* b1qkv  = (const float*)d_in[3];
    const float* w1o    = (const float*)d_in[4];
    const float* b1o    = (const float*)d_in[5];
    const float* w2qkv  = (const float*)d_in[6];
    const float* b2qkv  = (const float*)d_in[7];
    const float* w2o    = (const float*)d_in[8];
    const float* b2o    = (const float*)d_in[9];
    const float* outw   = (const float*)d_in[10];
    const float* outb   = (const float*)d_in[11];
    float* out = (float*)d_out;

    const int* srcp = ei;        // edge_index[0]
    const int* dstp = ei + NE;   // edge_index[1]

    // Workspace: q fp32 (10.24MB), kv bf16 interleaved (10.24MB),
    // accum fp32 (10.24MB), CSR ints (~1.5MB). hbuf aliases q (safe:
    // per-node blocks read row n before writing row n; disjoint rows).
    float*  q     = (float*)d_ws;
    ushort* kvb   = (ushort*)(q + NFD);
    float*  accum = (float*)(kvb + NN * 256);
    float*  hbuf  = q;  // alias
    int*    deg      = (int*)(accum + NFD);
    int*    rowstart = deg + NN;          // NN+1 entries
    int*    cursor   = rowstart + NN + 1;
    int*    csr_src  = cursor + NN;

    // Build CSR (once; shared by both layers)
    hipMemsetAsync(deg, 0, NN * sizeof(int), stream);
    deg_kernel<<<(NE + 255) / 256, 256, 0, stream>>>(dstp, deg);
    scan_kernel<<<1, 1024, 0, stream>>>(deg, rowstart, cursor);
    scatter_kernel<<<(NE + 255) / 256, 256, 0, stream>>>(srcp, dstp, cursor, csr_src);

    // Layer 1
    qkv_kernel<<<NN, 128, 0, stream>>>(x, w1qkv, b1qkv, q, kvb);
    edge_agg_kernel<<<NN / 4, 256, 0, stream>>>(rowstart, csr_src, q, kvb, accum);
    node_post_kernel<<<NN, 128, 0, stream>>>(accum, deg, w1o, b1o, hbuf);

    // Layer 2
    qkv_kernel<<<NN, 128, 0, stream>>>(hbuf, w2qkv, b2qkv, q, kvb);
    edge_agg_kernel<<<NN / 4, 256, 0, stream>>>(rowstart, csr_src, q, kvb, accum);
    node_post_kernel<<<NN, 128, 0, stream>>>(accum, deg, w2o, b2o, hbuf);

    // Output head
    classifier_kernel<<<(NN + 3) / 4, 256, 0, stream>>>(hbuf, outw, outb, out);
}